// Round 6
// baseline (72.835 us; speedup 1.0000x reference)
//
#include <hip/hip_runtime.h>

#define NELEC 64
#define NDIM 3
#define BPB 4                 // batches per block (1 wave = 1 batch)
#define BLOCK (BPB * NELEC)   // 256 threads

#if defined(__has_builtin)
#if __has_builtin(__builtin_amdgcn_rsqf)
#define RSQ(x) __builtin_amdgcn_rsqf(x)
#endif
#endif
#ifndef RSQ
#define RSQ(x) rsqrtf(x)
#endif

__global__ __launch_bounds__(BLOCK) void backflow_kernel(
    const float* __restrict__ pos, const float* __restrict__ w,
    float* __restrict__ out, int B)
{
    const int t = threadIdx.x;
    const int i = t & 63;                      // electron index
    const int b = blockIdx.x * BPB + (t >> 6); // wave id == batch
    if (b >= B) return;                        // no barriers below -> safe

    // Pin the batch index to an SGPR: the whole r_j sweep below is then a
    // uniform-address read stream, eligible for s_load through the constant
    // cache (zero LDS/VMEM ops in the hot loop). Fallback if the compiler
    // declines: wave-uniform VMEM broadcasts from L2-hot lines (~= old cost).
    const int bu = __builtin_amdgcn_readfirstlane(b);
    const float* __restrict__ rbase = pos + bu * (NELEC * NDIM);

    // own electron: per-lane 12B load, wave covers 768 contiguous B (coalesced)
    const float* p = rbase + i * NDIM;
    const float rx = p[0], ry = p[1], rz = p[2];

    const float wv = w[0];                     // uniform -> s_load

    // split accumulators: halves the serial fma dependency chain
    float ax0 = 0.f, ay0 = 0.f, az0 = 0.f;
    float ax1 = 0.f, ay1 = 0.f, az1 = 0.f;

    // unroll 16 => 48 uniform floats live per chunk (3x s_load_dwordx16),
    // comfortably inside the SGPR budget
    #pragma unroll 16
    for (int j = 0; j < NELEC; j += 2) {
        const float rjx0 = rbase[3*j + 0];     // wave-uniform -> SGPR
        const float rjy0 = rbase[3*j + 1];
        const float rjz0 = rbase[3*j + 2];
        const float rjx1 = rbase[3*j + 3];
        const float rjy1 = rbase[3*j + 4];
        const float rjz1 = rbase[3*j + 5];

        float dx0 = rx - rjx0, dy0 = ry - rjy0, dz0 = rz - rjz0;
        float dx1 = rx - rjx1, dy1 = ry - rjy1, dz1 = rz - rjz1;
        float d20 = dx0*dx0 + dy0*dy0 + dz0*dz0;
        float d21 = dx1*dx1 + dy1*dy1 + dz1*dz1;
        // j==i: delta==0 exactly -> finite*0 == 0; clamp keeps rsq finite at
        // d2==0; for j!=i, d2 >> 1e-37 so bit-identical to rsq(d2).
        float inv0 = RSQ(fmaxf(d20, 1e-37f));
        float inv1 = RSQ(fmaxf(d21, 1e-37f));
        ax0 += inv0 * dx0; ay0 += inv0 * dy0; az0 += inv0 * dz0;
        ax1 += inv1 * dx1; ay1 += inv1 * dy1; az1 += inv1 * dz1;
    }

    const float ax = ax0 + ax1, ay = ay0 + ay1, az = az0 + az1;
    float* dst = out + b * (NELEC * NDIM) + i * NDIM;  // 12B/lane, coalesced
    dst[0] = fmaf(wv, ax, rx);
    dst[1] = fmaf(wv, ay, ry);
    dst[2] = fmaf(wv, az, rz);
}

extern "C" void kernel_launch(void* const* d_in, const int* in_sizes, int n_in,
                              void* d_out, int out_size, void* d_ws, size_t ws_size,
                              hipStream_t stream) {
    const float* pos = (const float*)d_in[0];
    const float* w   = (const float*)d_in[1];
    float* out       = (float*)d_out;
    const int B = in_sizes[0] / (NELEC * NDIM);
    const int grid = (B + BPB - 1) / BPB;
    backflow_kernel<<<dim3(grid), dim3(BLOCK), 0, stream>>>(pos, w, out, B);
}